// Round 2
// baseline (231.811 us; speedup 1.0000x reference)
//
#include <hip/hip_runtime.h>

#define NNODES 8192
#define NEDGES 16384
#define DD 128
#define RR 64
#define BB 16
#define MAXTILES 576   // sum ceil(n_r/32) <= 16384/32 + 64 = 576

// ws layout (4-byte units)
#define FW_OFF     0                          // 64*128*128 fp32 combined weights
#define SWT_OFF    (RR*DD*DD)                 // 128*128 fp32 self_weight^T
#define CNT_OFF    (SWT_OFF + DD*DD)          // 8192*64 fp32 per-(tgt,rel) counts
#define HIST_OFF   (CNT_OFF + NNODES*RR)      // 64 int  per-relation edge counts
#define CURS_OFF   (HIST_OFF + RR)            // 64 int  scatter cursors
#define NTILES_OFF (CURS_OFF + RR)            // 1 int
#define SORT_OFF   (NTILES_OFF + 1)           // 16384 int relation-sorted edge ids
#define TILE_OFF   (SORT_OFF + NEDGES)        // 576*3 int (rel, base, cnt)

// Grid: [0,1024) fw combine, 1024 swT transpose, [1025,1089) histogram+counts
__global__ __launch_bounds__(256) void prep_kernel(
    const float* __restrict__ weight, const float* __restrict__ w_comp,
    const float* __restrict__ self_weight, const int* __restrict__ deprel,
    const int* __restrict__ edge_index, float* __restrict__ ws) {
  const int blk = blockIdx.x, tid = threadIdx.x;
  if (blk < 1024) {
    const int r = blk >> 4;
    const int ij0 = (blk & 15) * 1024 + tid * 4;
    const float* wc = w_comp + r * BB;
    float4 acc = {0.f, 0.f, 0.f, 0.f};
#pragma unroll
    for (int b = 0; b < BB; ++b) {
      float c = wc[b];
      float4 w = *reinterpret_cast<const float4*>(weight + b * DD * DD + ij0);
      acc.x += c * w.x; acc.y += c * w.y; acc.z += c * w.z; acc.w += c * w.w;
    }
    *reinterpret_cast<float4*>(ws + FW_OFF + r * DD * DD + ij0) = acc;
  } else if (blk == 1024) {
#pragma unroll 4
    for (int k = 0; k < 64; ++k) {
      int idx = k * 256 + tid;           // idx = i*128 + j
      int i = idx >> 7, j = idx & 127;
      ws[SWT_OFF + idx] = self_weight[j * DD + i];
    }
  } else {
    int e = (blk - 1025) * 256 + tid;
    int rel = deprel[e];
    int tgt = edge_index[NEDGES + e];
    atomicAdd(ws + CNT_OFF + tgt * RR + rel, 1.0f);
    atomicAdd((int*)ws + HIST_OFF + rel, 1);
  }
}

// 1 wave: prefix-scan relation histogram -> cursors + balanced tile table
__global__ void plan_kernel(float* __restrict__ wsf) {
  int* ws = (int*)wsf;
  const int r = threadIdx.x;          // 64 threads
  const int n = ws[HIST_OFF + r];
  const int nt = (n + 31) >> 5;
  int ei = n, ti = nt;                // inclusive scans over 64 lanes
#pragma unroll
  for (int d = 1; d < 64; d <<= 1) {
    int ev = __shfl_up(ei, d, 64);
    int tv = __shfl_up(ti, d, 64);
    if (r >= d) { ei += ev; ti += tv; }
  }
  const int e0 = ei - n, t0 = ti - nt;
  ws[CURS_OFF + r] = e0;
  for (int k = 0; k < nt; ++k) {
    int* te = ws + TILE_OFF + (t0 + k) * 3;
    te[0] = r;
    te[1] = e0 + k * 32;
    te[2] = min(32, n - k * 32);
  }
  if (r == 63) ws[NTILES_OFF] = ti;
}

__global__ __launch_bounds__(256) void scatter_kernel(
    const int* __restrict__ deprel, float* __restrict__ wsf) {
  int* ws = (int*)wsf;
  int e = blockIdx.x * 256 + threadIdx.x;
  int rel = deprel[e];
  int p = atomicAdd(ws + CURS_OFF + rel, 1);
  ws[SORT_OFF + p] = e;
}

// out[n][j] = bias[j] + sum_i inp[n][i]*swT[i][j]; 16 nodes/block, 512 blocks
__global__ __launch_bounds__(256) void self_kernel(
    const float* __restrict__ inp, const float* __restrict__ ws,
    const float* __restrict__ bias, float* __restrict__ out) {
  const float* swT = ws + SWT_OFF;
  const int tid = threadIdx.x;
  const int jq = tid & 15, mg = tid >> 4;
  const int n = blockIdx.x * 16 + mg;
  const int j0 = jq * 8;
  const float* x = inp + n * DD;
  float acc[8] = {};
#pragma unroll 4
  for (int i = 0; i < DD; ++i) {
    float xa = x[i];
    float4 w0 = *reinterpret_cast<const float4*>(swT + i * DD + j0);
    float4 w1 = *reinterpret_cast<const float4*>(swT + i * DD + j0 + 4);
    acc[0] += xa * w0.x; acc[1] += xa * w0.y; acc[2] += xa * w0.z; acc[3] += xa * w0.w;
    acc[4] += xa * w1.x; acc[5] += xa * w1.y; acc[6] += xa * w1.z; acc[7] += xa * w1.w;
  }
  float4 b0 = *reinterpret_cast<const float4*>(bias + j0);
  float4 b1 = *reinterpret_cast<const float4*>(bias + j0 + 4);
  float4 o0 = {acc[0] + b0.x, acc[1] + b0.y, acc[2] + b0.z, acc[3] + b0.w};
  float4 o1 = {acc[4] + b1.x, acc[5] + b1.y, acc[6] + b1.z, acc[7] + b1.w};
  *reinterpret_cast<float4*>(out + n * DD + j0) = o0;
  *reinterpret_cast<float4*>(out + n * DD + j0 + 4) = o1;
}

// One <=32-edge tile per block from the tile table; acc[2 edges][8 cols]/thread
__global__ __launch_bounds__(256) void edge_kernel(
    const float* __restrict__ inp, const int* __restrict__ edge_index,
    const float* __restrict__ wsf, float* __restrict__ out) {
  const int* wsi = (const int*)wsf;
  __shared__ int s_src[32], s_tgt[32];
  __shared__ float s_scale[32];
  const int tile = blockIdx.x;
  if (tile >= wsi[NTILES_OFF]) return;
  const int rel  = wsi[TILE_OFF + tile * 3];
  const int base = wsi[TILE_OFF + tile * 3 + 1];
  const int cnt  = wsi[TILE_OFF + tile * 3 + 2];
  const int tid = threadIdx.x;
  if (tid < 32) {
    if (tid < cnt) {
      int e = wsi[SORT_OFF + base + tid];
      int s = edge_index[e];
      int t = edge_index[NEDGES + e];
      s_src[tid] = s; s_tgt[tid] = t;
      s_scale[tid] = 1.0f / wsf[CNT_OFF + t * RR + rel];
    } else {
      s_src[tid] = 0; s_tgt[tid] = 0; s_scale[tid] = 0.f;
    }
  }
  __syncthreads();
  const float* W = wsf + FW_OFF + rel * DD * DD;
  const int jq = tid & 15, mg = tid >> 4;
  const int j0 = jq * 8, m0 = mg * 2;
  const float* xa = inp + s_src[m0] * DD;
  const float* xb = inp + s_src[m0 + 1] * DD;
  float acc[2][8] = {};
#pragma unroll 4
  for (int i = 0; i < DD; ++i) {
    float a = xa[i], b = xb[i];
    float4 w0 = *reinterpret_cast<const float4*>(W + i * DD + j0);
    float4 w1 = *reinterpret_cast<const float4*>(W + i * DD + j0 + 4);
    acc[0][0] += a * w0.x; acc[0][1] += a * w0.y; acc[0][2] += a * w0.z; acc[0][3] += a * w0.w;
    acc[0][4] += a * w1.x; acc[0][5] += a * w1.y; acc[0][6] += a * w1.z; acc[0][7] += a * w1.w;
    acc[1][0] += b * w0.x; acc[1][1] += b * w0.y; acc[1][2] += b * w0.z; acc[1][3] += b * w0.w;
    acc[1][4] += b * w1.x; acc[1][5] += b * w1.y; acc[1][6] += b * w1.z; acc[1][7] += b * w1.w;
  }
#pragma unroll
  for (int mi = 0; mi < 2; ++mi) {
    int m = m0 + mi;
    if (m < cnt) {
      float sc = s_scale[m];
      float* orow = out + s_tgt[m] * DD + j0;
#pragma unroll
      for (int k = 0; k < 8; ++k) atomicAdd(orow + k, acc[mi][k] * sc);
    }
  }
}

extern "C" void kernel_launch(void* const* d_in, const int* in_sizes, int n_in,
                              void* d_out, int out_size, void* d_ws, size_t ws_size,
                              hipStream_t stream) {
  const float* inp        = (const float*)d_in[0];
  const int*   deprel     = (const int*)d_in[1];
  const int*   edge_index = (const int*)d_in[2];
  const float* weight     = (const float*)d_in[3];
  const float* w_comp     = (const float*)d_in[4];
  const float* self_w     = (const float*)d_in[5];
  const float* bias       = (const float*)d_in[6];
  float* out = (float*)d_out;
  float* ws  = (float*)d_ws;

  // zero counts + histogram (contiguous region)
  hipMemsetAsync((char*)d_ws + (size_t)CNT_OFF * 4, 0,
                 (size_t)(NNODES * RR + RR) * 4, stream);
  prep_kernel<<<1089, 256, 0, stream>>>(weight, w_comp, self_w, deprel, edge_index, ws);
  plan_kernel<<<1, 64, 0, stream>>>(ws);
  scatter_kernel<<<NEDGES / 256, 256, 0, stream>>>(deprel, ws);
  self_kernel<<<NNODES / 16, 256, 0, stream>>>(inp, ws, bias, out);
  edge_kernel<<<MAXTILES, 256, 0, stream>>>(inp, edge_index, ws, out);
}

// Round 4
// 159.664 us; speedup vs baseline: 1.4519x; 1.4519x over previous
//
#include <hip/hip_runtime.h>

#define NNODES 8192
#define NEDGES 16384
#define DD 128
#define RR 64
#define BB 16

typedef __attribute__((ext_vector_type(8))) short bf16x8;
typedef __attribute__((ext_vector_type(4))) float f32x4;

// ---- ws layout, offsets in 4-byte words ----
#define FWB_OFF   0                 // bf16 fwbT[64][128][128]  (n-major, k-contig)  524288 w
#define INPB_OFF  524288            // bf16 inp_b[8192][128]                          524288 w
#define SWB_OFF   1048576           // bf16 swb[128][128] (row-major = B-frag layout)   8192 w
#define Y_OFF     1056768           // f32 Y[16384][128] per-edge messages          2097152 w
#define CNT_OFF   3153920           // f32 cnt[8192*64] per-(tgt,rel)                524288 w
#define RH_OFF    3678208           // int relHist[64]
#define TH_OFF    3678272           // int tgtHist[8192]
#define CR_OFF    3686464           // int relCursor[64]
#define CT_OFF    3686528           // int tgtCursor[8192]
#define NT_OFF    3694720           // int ntiles
#define TOFF_OFF  3694721           // int tgtOff[8192]
#define SORTR_OFF 3702913           // int sortR[16384]
#define SORTT_OFF 3719297           // int sortT[16384]
#define TILE_OFF  3735681           // int tile[1088][3] = (rel, base, cnt)
#define ZERO_BEG  CNT_OFF
#define ZERO_WORDS (NT_OFF + 1 - CNT_OFF)
#define MAX_ETILES 1088
#define GEMM_WAVES (512 + MAX_ETILES)

static __device__ __forceinline__ unsigned short f2bf(float f) {
  union { float f; unsigned u; } v; v.f = f;
  unsigned r = v.u + 0x7FFFu + ((v.u >> 16) & 1u);   // RNE
  return (unsigned short)(r >> 16);
}

// grid 2128: [0,1024) fwbT combine+transpose+cast; [1024,2048) inp cast;
//            [2048,2064) self_w cast; [2064,2128) histograms
__global__ __launch_bounds__(256) void prep_kernel(
    const float* __restrict__ inp, const int* __restrict__ deprel,
    const int* __restrict__ edge_index, const float* __restrict__ weight,
    const float* __restrict__ w_comp, const float* __restrict__ self_w,
    float* __restrict__ ws_f) {
  const int blk = blockIdx.x, t = threadIdx.x;
  if (blk < 1024) {
    __shared__ float fl[32][33];
    const int r = blk >> 4, tile = blk & 15;
    const int k0 = (tile >> 2) * 32, n0 = (tile & 3) * 32;
    const int kl = t >> 3, nl4 = (t & 7) * 4;
    const float* wc = w_comp + r * BB;
    float4 acc = {0.f, 0.f, 0.f, 0.f};
#pragma unroll
    for (int b = 0; b < BB; ++b) {
      float c = wc[b];
      float4 w = *(const float4*)(weight + b * DD * DD + (k0 + kl) * DD + n0 + nl4);
      acc.x += c * w.x; acc.y += c * w.y; acc.z += c * w.z; acc.w += c * w.w;
    }
    fl[nl4 + 0][kl] = acc.x; fl[nl4 + 1][kl] = acc.y;
    fl[nl4 + 2][kl] = acc.z; fl[nl4 + 3][kl] = acc.w;
    __syncthreads();
    const int nl = t >> 3, kq = (t & 7) * 4;
    unsigned short* dst = (unsigned short*)(ws_f + FWB_OFF) + r * DD * DD + (n0 + nl) * DD + k0 + kq;
    *(ushort4*)dst = make_ushort4(f2bf(fl[nl][kq + 0]), f2bf(fl[nl][kq + 1]),
                                  f2bf(fl[nl][kq + 2]), f2bf(fl[nl][kq + 3]));
  } else if (blk < 2048) {
    int idx = (blk - 1024) * 1024 + t * 4;
    float4 v = *(const float4*)(inp + idx);
    unsigned short* dst = (unsigned short*)(ws_f + INPB_OFF) + idx;
    *(ushort4*)dst = make_ushort4(f2bf(v.x), f2bf(v.y), f2bf(v.z), f2bf(v.w));
  } else if (blk < 2064) {
    int idx = (blk - 2048) * 1024 + t * 4;
    float4 v = *(const float4*)(self_w + idx);
    unsigned short* dst = (unsigned short*)(ws_f + SWB_OFF) + idx;
    *(ushort4*)dst = make_ushort4(f2bf(v.x), f2bf(v.y), f2bf(v.z), f2bf(v.w));
  } else {
    int e = (blk - 2064) * 256 + t;
    int rel = deprel[e];
    int tgt = edge_index[NEDGES + e];
    atomicAdd(ws_f + CNT_OFF + tgt * RR + rel, 1.0f);
    atomicAdd((int*)ws_f + RH_OFF + rel, 1);
    atomicAdd((int*)ws_f + TH_OFF + tgt, 1);
  }
}

// single block: target prefix-scan (CSR) + relation prefix-scan + tile table
__global__ void plan_kernel(float* __restrict__ ws_f) {
  int* ws = (int*)ws_f;
  __shared__ int part[256];
  const int t = threadIdx.x;
  const int base = t * 32;
  int s = 0;
  for (int k = 0; k < 32; ++k) s += ws[TH_OFF + base + k];
  part[t] = s;
  __syncthreads();
  if (t == 0) {
    int run = 0;
    for (int i = 0; i < 256; ++i) { int v = part[i]; part[i] = run; run += v; }
  }
  __syncthreads();
  int run = part[t];
  for (int k = 0; k < 32; ++k) {
    int v = ws[TH_OFF + base + k];
    ws[TOFF_OFF + base + k] = run;
    ws[CT_OFF + base + k] = run;
    run += v;
  }
  if (t < 64) {   // wave 0 only
    int n = ws[RH_OFF + t];
    int nt = (n + 15) >> 4;
    int ei = n, ti = nt;
#pragma unroll
    for (int d = 1; d < 64; d <<= 1) {
      int e2 = __shfl_up(ei, d, 64);
      int t2 = __shfl_up(ti, d, 64);
      if (t >= d) { ei += e2; ti += t2; }
    }
    int e0 = ei - n, t0 = ti - nt;
    ws[CR_OFF + t] = e0;
    for (int k = 0; k < nt; ++k) {
      int* te = ws + TILE_OFF + (t0 + k) * 3;
      te[0] = t; te[1] = e0 + k * 16; te[2] = min(16, n - k * 16);
    }
    if (t == 63) ws[NT_OFF] = ti;
  }
}

__global__ __launch_bounds__(256) void scatter_kernel(
    const int* __restrict__ deprel, const int* __restrict__ edge_index,
    float* __restrict__ ws_f) {
  int* ws = (int*)ws_f;
  int e = blockIdx.x * 256 + threadIdx.x;
  int rel = deprel[e];
  int tgt = edge_index[NEDGES + e];
  int pR = atomicAdd(ws + CR_OFF + rel, 1); ws[SORTR_OFF + pR] = e;
  int pT = atomicAdd(ws + CT_OFF + tgt, 1); ws[SORTT_OFF + pT] = e;
}

// 1600 waves: [0,512) self tiles -> out (plain store, incl bias);
//             [512, 512+ntiles) edge tiles -> Y (plain store, scaled)
__global__ __launch_bounds__(256) void gemm_kernel(
    const float* __restrict__ bias, const int* __restrict__ edge_index,
    float* __restrict__ ws_f, float* __restrict__ out) {
  const int* wsi = (const int*)ws_f;
  const int lane = threadIdx.x & 63;
  const int wave = blockIdx.x * 4 + (threadIdx.x >> 6);
  const int ln = lane & 15, q = lane >> 4;
  const unsigned short* inpb = (const unsigned short*)(ws_f + INPB_OFF);

  if (wave < 512) {
    const int m0 = wave * 16;
    const unsigned short* arow = inpb + (m0 + ln) * DD;
    bf16x8 a[4];
#pragma unroll
    for (int kk = 0; kk < 4; ++kk)
      a[kk] = *(const bf16x8*)(arow + kk * 32 + q * 8);
    const unsigned short* swb = (const unsigned short*)(ws_f + SWB_OFF);
#pragma unroll
    for (int nt = 0; nt < 8; ++nt) {
      const int n0 = nt * 16;
      f32x4 acc = {0.f, 0.f, 0.f, 0.f};
      const unsigned short* brow = swb + (n0 + ln) * DD + q * 8;
#pragma unroll
      for (int kk = 0; kk < 4; ++kk) {
        bf16x8 b = *(const bf16x8*)(brow + kk * 32);
        acc = __builtin_amdgcn_mfma_f32_16x16x32_bf16(a[kk], b, acc, 0, 0, 0);
      }
      float bv = bias[n0 + ln];
#pragma unroll
      for (int v = 0; v < 4; ++v)
        out[(m0 + q * 4 + v) * DD + n0 + ln] = acc[v] + bv;
    }
  } else {
    const int et = wave - 512;
    if (et >= wsi[NT_OFF]) return;
    const int* te = wsi + TILE_OFF + et * 3;
    const int rel = te[0], base = te[1], cnt = te[2];
    const int e_m = wsi[SORTR_OFF + base + min(ln, cnt - 1)];
    const int s_m = edge_index[e_m];
    const int t_m = edge_index[NEDGES + e_m];
    const float sc_m = 1.0f / ws_f[CNT_OFF + t_m * RR + rel];
    bf16x8 a[4];
    const unsigned short* arow = inpb + s_m * DD;
#pragma unroll
    for (int kk = 0; kk < 4; ++kk)
      a[kk] = *(const bf16x8*)(arow + kk * 32 + q * 8);
    int ev[4]; float sv[4];
#pragma unroll
    for (int v = 0; v < 4; ++v) {
      int m = q * 4 + v;
      ev[v] = __shfl(e_m, m);
      sv[v] = __shfl(sc_m, m);
    }
    const unsigned short* fwb = (const unsigned short*)(ws_f + FWB_OFF) + rel * DD * DD;
    float* Yf = ws_f + Y_OFF;
#pragma unroll
    for (int nt = 0; nt < 8; ++nt) {
      const int n0 = nt * 16;
      f32x4 acc = {0.f, 0.f, 0.f, 0.f};
      const unsigned short* brow = fwb + (n0 + ln) * DD + q * 8;
#pragma unroll
      for (int kk = 0; kk < 4; ++kk) {
        bf16x8 b = *(const bf16x8*)(brow + kk * 32);
        acc = __builtin_amdgcn_mfma_f32_16x16x32_bf16(a[kk], b, acc, 0, 0, 0);
      }
#pragma unroll
      for (int v = 0; v < 4; ++v) {
        int m = q * 4 + v;
        if (m < cnt) Yf[ev[v] * DD + n0 + ln] = acc[v] * sv[v];
      }
    }
  }
}

// thread = (node, col4): out[node] += sum_{e in-edges(node)} Y[e]
__global__ __launch_bounds__(256) void reduce_kernel(
    const float* __restrict__ ws_f, float* __restrict__ out) {
  const int* wsi = (const int*)ws_f;
  const int t = blockIdx.x * 256 + threadIdx.x;
  const int node = t >> 5, c = (t & 31) * 4;
  float4 acc = *(float4*)(out + node * DD + c);
  const int off = wsi[TOFF_OFF + node];
  const int ne = wsi[TH_OFF + node];
  const float* Yf = ws_f + Y_OFF;
  for (int j = 0; j < ne; ++j) {
    int e = wsi[SORTT_OFF + off + j];
    float4 y = *(const float4*)(Yf + e * DD + c);
    acc.x += y.x; acc.y += y.y; acc.z += y.z; acc.w += y.w;
  }
  *(float4*)(out + node * DD + c) = acc;
}

extern "C" void kernel_launch(void* const* d_in, const int* in_sizes, int n_in,
                              void* d_out, int out_size, void* d_ws, size_t ws_size,
                              hipStream_t stream) {
  const float* inp        = (const float*)d_in[0];
  const int*   deprel     = (const int*)d_in[1];
  const int*   edge_index = (const int*)d_in[2];
  const float* weight     = (const float*)d_in[3];
  const float* w_comp     = (const float*)d_in[4];
  const float* self_w     = (const float*)d_in[5];
  const float* bias       = (const float*)d_in[6];
  float* out = (float*)d_out;
  float* ws  = (float*)d_ws;

  hipMemsetAsync((char*)d_ws + (size_t)ZERO_BEG * 4, 0, (size_t)ZERO_WORDS * 4, stream);
  prep_kernel<<<2128, 256, 0, stream>>>(inp, deprel, edge_index, weight, w_comp, self_w, ws);
  plan_kernel<<<1, 256, 0, stream>>>(ws);
  scatter_kernel<<<NEDGES / 256, 256, 0, stream>>>(deprel, edge_index, ws);
  gemm_kernel<<<(GEMM_WAVES + 3) / 4, 256, 0, stream>>>(bias, edge_index, ws, out);
  reduce_kernel<<<NNODES * 32 / 256, 256, 0, stream>>>(ws, out);
}

// Round 5
// 157.716 us; speedup vs baseline: 1.4698x; 1.0123x over previous
//
#include <hip/hip_runtime.h>

#define NNODES 8192
#define NEDGES 16384
#define DD 128
#define RR 64
#define BB 16

typedef __attribute__((ext_vector_type(8))) short bf16x8;
typedef __attribute__((ext_vector_type(4))) float f32x4;

// ---- ws layout, offsets in 4-byte words ----
#define FWB_OFF   0                 // bf16 fwbT[64][128][128] (n-major, k-contig)
#define INPB_OFF  524288            // bf16 inp_b[8192][128]
#define SWB_OFF   1048576           // bf16 swb[128][128]
#define Y_OFF     1056768           // f32 Y[16384][128], indexed by target-sorted pos
#define RH_OFF    3153920           // int relHist[64]
#define TH_OFF    3153984           // int tgtHist[8192]
#define CR_OFF    3162176           // int relCursor[64]
#define CT_OFF    3162240           // int tgtCursor[8192]
#define NT_OFF    3170432           // int ntiles
#define TOFF_OFF  3170433           // int tgtOff[8192]
#define POS_OFF   3178625           // int posT[e] : edge -> target-sorted slot
#define RELT_OFF  3195009           // int rel per target-sorted slot
#define SORTR_OFF 3211393           // int relation-sorted edge ids
#define TILE_OFF  3227777           // int tile[1088][3] = (rel, base, cnt)
#define ZERO_BEG  RH_OFF
#define ZERO_WORDS (64 + 8192)
#define MAX_ETILES 1088
#define GEMM_WAVES (1024 + 2 * MAX_ETILES)   // 2 waves per 16-row tile

static __device__ __forceinline__ unsigned short f2bf(float f) {
  union { float f; unsigned u; } v; v.f = f;
  unsigned r = v.u + 0x7FFFu + ((v.u >> 16) & 1u);   // RNE
  return (unsigned short)(r >> 16);
}

// grid 2128: [0,1024) fwbT combine+transpose+cast; [1024,2048) inp cast;
//            [2048,2064) self_w cast; [2064,2128) histograms
__global__ __launch_bounds__(256) void prep_kernel(
    const float* __restrict__ inp, const int* __restrict__ deprel,
    const int* __restrict__ edge_index, const float* __restrict__ weight,
    const float* __restrict__ w_comp, const float* __restrict__ self_w,
    float* __restrict__ ws_f) {
  const int blk = blockIdx.x, t = threadIdx.x;
  if (blk < 1024) {
    __shared__ float fl[32][33];
    const int r = blk >> 4, tile = blk & 15;
    const int k0 = (tile >> 2) * 32, n0 = (tile & 3) * 32;
    const int kl = t >> 3, nl4 = (t & 7) * 4;
    const float* wc = w_comp + r * BB;
    float4 acc = {0.f, 0.f, 0.f, 0.f};
#pragma unroll
    for (int b = 0; b < BB; ++b) {
      float c = wc[b];
      float4 w = *(const float4*)(weight + b * DD * DD + (k0 + kl) * DD + n0 + nl4);
      acc.x += c * w.x; acc.y += c * w.y; acc.z += c * w.z; acc.w += c * w.w;
    }
    fl[nl4 + 0][kl] = acc.x; fl[nl4 + 1][kl] = acc.y;
    fl[nl4 + 2][kl] = acc.z; fl[nl4 + 3][kl] = acc.w;
    __syncthreads();
    const int nl = t >> 3, kq = (t & 7) * 4;
    unsigned short* dst = (unsigned short*)(ws_f + FWB_OFF) + r * DD * DD + (n0 + nl) * DD + k0 + kq;
    *(ushort4*)dst = make_ushort4(f2bf(fl[nl][kq + 0]), f2bf(fl[nl][kq + 1]),
                                  f2bf(fl[nl][kq + 2]), f2bf(fl[nl][kq + 3]));
  } else if (blk < 2048) {
    int idx = (blk - 1024) * 1024 + t * 4;
    float4 v = *(const float4*)(inp + idx);
    unsigned short* dst = (unsigned short*)(ws_f + INPB_OFF) + idx;
    *(ushort4*)dst = make_ushort4(f2bf(v.x), f2bf(v.y), f2bf(v.z), f2bf(v.w));
  } else if (blk < 2064) {
    int idx = (blk - 2048) * 1024 + t * 4;
    float4 v = *(const float4*)(self_w + idx);
    unsigned short* dst = (unsigned short*)(ws_f + SWB_OFF) + idx;
    *(ushort4*)dst = make_ushort4(f2bf(v.x), f2bf(v.y), f2bf(v.z), f2bf(v.w));
  } else {
    int e = (blk - 2064) * 256 + t;
    int rel = deprel[e];
    int tgt = edge_index[NEDGES + e];
    atomicAdd((int*)ws_f + RH_OFF + rel, 1);
    atomicAdd((int*)ws_f + TH_OFF + tgt, 1);
  }
}

// single block: target CSR scan (parallel) + relation scan + tile table
__global__ void plan_kernel(float* __restrict__ ws_f) {
  int* ws = (int*)ws_f;
  __shared__ int part[256];
  const int t = threadIdx.x;
  const int base = t * 32;
  int s = 0;
#pragma unroll
  for (int k = 0; k < 32; ++k) s += ws[TH_OFF + base + k];
  part[t] = s;
  __syncthreads();
  if (t < 64) {   // wave 0: exclusive scan of 256 partials, 4 per lane
    int p0 = part[4 * t], p1 = part[4 * t + 1], p2 = part[4 * t + 2], p3 = part[4 * t + 3];
    int sum4 = p0 + p1 + p2 + p3;
    int inc = sum4;
#pragma unroll
    for (int d = 1; d < 64; d <<= 1) {
      int v = __shfl_up(inc, d, 64);
      if (t >= d) inc += v;
    }
    int excl = inc - sum4;
    part[4 * t] = excl;
    part[4 * t + 1] = excl + p0;
    part[4 * t + 2] = excl + p0 + p1;
    part[4 * t + 3] = excl + p0 + p1 + p2;
  }
  __syncthreads();
  int run = part[t];
  for (int k = 0; k < 32; ++k) {
    int v = ws[TH_OFF + base + k];
    ws[TOFF_OFF + base + k] = run;
    ws[CT_OFF + base + k] = run;
    run += v;
  }
  if (t < 64) {   // wave 0: relation scan + tile table
    int n = ws[RH_OFF + t];
    int nt = (n + 15) >> 4;
    int ei = n, ti = nt;
#pragma unroll
    for (int d = 1; d < 64; d <<= 1) {
      int e2 = __shfl_up(ei, d, 64);
      int t2 = __shfl_up(ti, d, 64);
      if (t >= d) { ei += e2; ti += t2; }
    }
    int e0 = ei - n, t0 = ti - nt;
    ws[CR_OFF + t] = e0;
    for (int k = 0; k < nt; ++k) {
      int* te = ws + TILE_OFF + (t0 + k) * 3;
      te[0] = t; te[1] = e0 + k * 16; te[2] = min(16, n - k * 16);
    }
    if (t == 63) ws[NT_OFF] = ti;
  }
}

__global__ __launch_bounds__(256) void scatter_kernel(
    const int* __restrict__ deprel, const int* __restrict__ edge_index,
    float* __restrict__ ws_f) {
  int* ws = (int*)ws_f;
  int e = blockIdx.x * 256 + threadIdx.x;
  int rel = deprel[e];
  int tgt = edge_index[NEDGES + e];
  int pR = atomicAdd(ws + CR_OFF + rel, 1);
  ws[SORTR_OFF + pR] = e;
  int pT = atomicAdd(ws + CT_OFF + tgt, 1);
  ws[POS_OFF + e] = pT;
  ws[RELT_OFF + pT] = rel;
}

// 3200 waves: [0,1024) self half-tiles -> out; [1024,..) edge half-tiles -> Y
// Each 16-row tile is split across 2 waves (4 of 8 n-subtiles each).
__global__ __launch_bounds__(256) void gemm_kernel(
    const float* __restrict__ bias, const int* __restrict__ edge_index,
    float* __restrict__ ws_f, float* __restrict__ out) {
  const int* wsi = (const int*)ws_f;
  const int lane = threadIdx.x & 63;
  const int wave = blockIdx.x * 4 + (threadIdx.x >> 6);
  const int ln = lane & 15, q = lane >> 4;
  const unsigned short* inpb = (const unsigned short*)(ws_f + INPB_OFF);

  if (wave < 1024) {
    const int m0 = (wave >> 1) * 16;
    const int h = wave & 1;
    const unsigned short* arow = inpb + (m0 + ln) * DD;
    bf16x8 a[4];
#pragma unroll
    for (int kk = 0; kk < 4; ++kk)
      a[kk] = *(const bf16x8*)(arow + kk * 32 + q * 8);
    const unsigned short* swb = (const unsigned short*)(ws_f + SWB_OFF);
#pragma unroll
    for (int ntb = 0; ntb < 4; ++ntb) {
      const int n0 = (h * 4 + ntb) * 16;
      f32x4 acc = {0.f, 0.f, 0.f, 0.f};
      const unsigned short* brow = swb + (n0 + ln) * DD + q * 8;
#pragma unroll
      for (int kk = 0; kk < 4; ++kk) {
        bf16x8 b = *(const bf16x8*)(brow + kk * 32);
        acc = __builtin_amdgcn_mfma_f32_16x16x32_bf16(a[kk], b, acc, 0, 0, 0);
      }
      float bv = bias[n0 + ln];
#pragma unroll
      for (int v = 0; v < 4; ++v)
        out[(m0 + q * 4 + v) * DD + n0 + ln] = acc[v] + bv;
    }
  } else {
    const int w2 = wave - 1024;
    const int et = w2 >> 1, h = w2 & 1;
    if (et >= wsi[NT_OFF]) return;
    const int* te = wsi + TILE_OFF + et * 3;
    const int rel = te[0], base = te[1], cnt = te[2];
    const int e_m = wsi[SORTR_OFF + base + min(ln, cnt - 1)];
    const int s_m = edge_index[e_m];
    const int p_m = wsi[POS_OFF + e_m];
    bf16x8 a[4];
    const unsigned short* arow = inpb + s_m * DD;
#pragma unroll
    for (int kk = 0; kk < 4; ++kk)
      a[kk] = *(const bf16x8*)(arow + kk * 32 + q * 8);
    int pv[4];
#pragma unroll
    for (int v = 0; v < 4; ++v)
      pv[v] = __shfl(p_m, q * 4 + v);
    const unsigned short* fwb = (const unsigned short*)(ws_f + FWB_OFF) + rel * DD * DD;
    float* Yf = ws_f + Y_OFF;
#pragma unroll
    for (int ntb = 0; ntb < 4; ++ntb) {
      const int n0 = (h * 4 + ntb) * 16;
      f32x4 acc = {0.f, 0.f, 0.f, 0.f};
      const unsigned short* brow = fwb + (n0 + ln) * DD + q * 8;
#pragma unroll
      for (int kk = 0; kk < 4; ++kk) {
        bf16x8 b = *(const bf16x8*)(brow + kk * 32);
        acc = __builtin_amdgcn_mfma_f32_16x16x32_bf16(a[kk], b, acc, 0, 0, 0);
      }
#pragma unroll
      for (int v = 0; v < 4; ++v) {
        int m = q * 4 + v;
        if (m < cnt) Yf[pv[v] * DD + n0 + ln] = acc[v];
      }
    }
  }
}

// thread = (node, col4): out[node] += sum_j Y[off+j] / count(rel_j in node's list)
__global__ __launch_bounds__(256) void reduce_kernel(
    const float* __restrict__ ws_f, float* __restrict__ out) {
  const int* wsi = (const int*)ws_f;
  const int t = blockIdx.x * 256 + threadIdx.x;
  const int node = t >> 5, c = (t & 31) * 4;
  const int off = wsi[TOFF_OFF + node];
  const int ne = wsi[TH_OFF + node];
  float4 acc = *(float4*)(out + node * DD + c);
  const float* Yf = ws_f + Y_OFF;
  const int* relt = wsi + RELT_OFF + off;
  for (int j = 0; j < ne; ++j) {
    int rj = relt[j];
    int cj = 0;
    for (int k = 0; k < ne; ++k) cj += (relt[k] == rj) ? 1 : 0;
    float inv = 1.0f / (float)cj;
    float4 y = *(const float4*)(Yf + (off + j) * DD + c);
    acc.x += y.x * inv; acc.y += y.y * inv; acc.z += y.z * inv; acc.w += y.w * inv;
  }
  *(float4*)(out + node * DD + c) = acc;
}

extern "C" void kernel_launch(void* const* d_in, const int* in_sizes, int n_in,
                              void* d_out, int out_size, void* d_ws, size_t ws_size,
                              hipStream_t stream) {
  const float* inp        = (const float*)d_in[0];
  const int*   deprel     = (const int*)d_in[1];
  const int*   edge_index = (const int*)d_in[2];
  const float* weight     = (const float*)d_in[3];
  const float* w_comp     = (const float*)d_in[4];
  const float* self_w     = (const float*)d_in[5];
  const float* bias       = (const float*)d_in[6];
  float* out = (float*)d_out;
  float* ws  = (float*)d_ws;

  hipMemsetAsync((char*)d_ws + (size_t)ZERO_BEG * 4, 0, (size_t)ZERO_WORDS * 4, stream);
  prep_kernel<<<2128, 256, 0, stream>>>(inp, deprel, edge_index, weight, w_comp, self_w, ws);
  plan_kernel<<<1, 256, 0, stream>>>(ws);
  scatter_kernel<<<NEDGES / 256, 256, 0, stream>>>(deprel, edge_index, ws);
  gemm_kernel<<<GEMM_WAVES / 4, 256, 0, stream>>>(bias, edge_index, ws, out);
  reduce_kernel<<<NNODES * 32 / 256, 256, 0, stream>>>(ws, out);
}